// Round 6
// baseline (212.549 us; speedup 1.0000x reference)
//
#include <hip/hip_runtime.h>

#define MD   4
#define B_   4
#define C_   128
#define H_   128
#define W_   256
#define ND   9            // 2*MD+1 displacements per axis
#define NW   9            // waves per block, one per dy
#define XPT  4            // x pixels per lane (64 lanes cover W)

typedef float float4v __attribute__((ext_vector_type(4)));

// One wave per (b,y,dy). Halo via neighbor-lane shuffles (no LDS, no
// barriers). Explicit 2-deep channel-pair software pipeline so loads for
// channels c+2..c+3 are in flight while channels c..c+1 compute.
__global__ __launch_bounds__(NW * 64, 5)   // VGPR cap 102 -> 2 blocks/CU
void corr_kernel(const float* __restrict__ t1,
                 const float* __restrict__ t2,
                 float* __restrict__ out) {
    const int tid  = threadIdx.x;
    const int lane = tid & 63;
    const int w    = tid >> 6;                 // wave id == dy
    const int bid  = blockIdx.x;               // XCD swizzle (512 = 8*64)
    const int swz  = (bid & 7) * 64 + (bid >> 3);
    const int y    = swz & (H_ - 1);
    const int b    = swz >> 7;
    const int x0   = lane * XPT;               // 0..252
    const int yy   = y + w - MD;               // this wave's shifted t2 row
    const float scale = 1.0f / (float)C_;

    if (yy < 0 || yy >= H_) {                  // zero-pad region: output = 0
        float4v z = {0.f, 0.f, 0.f, 0.f};
        #pragma unroll
        for (int dx = 0; dx < ND; ++dx) {
            const size_t oidx =
                (((size_t)(b * ND * ND) + w * ND + dx) * H_ + y) * W_ + x0;
            *(float4v*)&out[oidx] = z;
        }
        return;
    }

    float acc[ND][XPT];
    #pragma unroll
    for (int dx = 0; dx < ND; ++dx)
        #pragma unroll
        for (int j = 0; j < XPT; ++j) acc[dx][j] = 0.0f;

    const float* p1 = t1 + (((size_t)(b * C_)) * H_ + y ) * W_ + x0;
    const float* p2 = t2 + (((size_t)(b * C_)) * H_ + yy) * W_ + x0;
    const size_t chstr = (size_t)H_ * W_;

    const bool lm = (lane == 0);    // window extends left of x=0  -> pad 0
    const bool rm = (lane == 63);   // window extends right of W-1 -> pad 0

    float4v A[2][2], V[2][2];       // [buf][channel-in-pair], static idx only

    auto LOADPAIR = [&](int buf, int c) {
        A[buf][0] = *(const float4v*)(p1 + (size_t)c * chstr);
        V[buf][0] = *(const float4v*)(p2 + (size_t)c * chstr);
        A[buf][1] = *(const float4v*)(p1 + (size_t)(c + 1) * chstr);
        V[buf][1] = *(const float4v*)(p2 + (size_t)(c + 1) * chstr);
    };

    auto COMP1 = [&](const float4v a, const float4v v) {
        // win[k] = t2 at x = x0 - 4 + k, k = 0..11
        float win[XPT + 2 * MD];
        #pragma unroll
        for (int k = 0; k < 4; ++k) {
            const float up = __shfl_up(v[k], 1);
            const float dn = __shfl_down(v[k], 1);
            win[k]     = lm ? 0.0f : up;
            win[4 + k] = v[k];
            win[8 + k] = rm ? 0.0f : dn;
        }
        #pragma unroll
        for (int dx = 0; dx < ND; ++dx)
            #pragma unroll
            for (int j = 0; j < XPT; ++j)
                acc[dx][j] = fmaf(a[j], win[dx + j], acc[dx][j]);
    };

    LOADPAIR(0, 0);                            // prologue: ch 0,1 in flight
    for (int c = 0; c < C_; c += 4) {
        LOADPAIR(1, c + 2);                    // prefetch ch c+2,c+3
        COMP1(A[0][0], V[0][0]);               // ch c
        COMP1(A[0][1], V[0][1]);               // ch c+1
        if (c + 4 < C_) LOADPAIR(0, c + 4);    // prefetch ch c+4,c+5
        COMP1(A[1][0], V[1][0]);               // ch c+2
        COMP1(A[1][1], V[1][1]);               // ch c+3
    }

    #pragma unroll
    for (int dx = 0; dx < ND; ++dx) {
        float4v o;
        #pragma unroll
        for (int j = 0; j < XPT; ++j) o[j] = acc[dx][j] * scale;
        const size_t oidx =
            (((size_t)(b * ND * ND) + w * ND + dx) * H_ + y) * W_ + x0;
        *(float4v*)&out[oidx] = o;
    }
}

extern "C" void kernel_launch(void* const* d_in, const int* in_sizes, int n_in,
                              void* d_out, int out_size, void* d_ws, size_t ws_size,
                              hipStream_t stream) {
    const float* t1 = (const float*)d_in[0];
    const float* t2 = (const float*)d_in[1];
    float* out      = (float*)d_out;
    corr_kernel<<<dim3(B_ * H_), NW * 64, 0, stream>>>(t1, t2, out);
}